// Round 16
// baseline (475.956 us; speedup 1.0000x reference)
//
#include <hip/hip_runtime.h>
#include <hip/hip_bf16.h>
#include <limits.h>

#define NNODES 100000
#define NEDGES 640000
#define WIDTH  128
#define NFEAT  64
#define KA     192          // edge GEMM K (128 diffs + 64 e_feat)
#define KA_PAD 196          // LDS row stride (bf16): 98 words, %32==2 -> 2-way (free)
                            // measured: 1.48M conflicts vs 5.3M at pad=200 (R1 vs R2)
#define KB     256          // node GEMM K (128 x + 128 maxes)
#define KB_PAD 264
#define MT     64           // rows per tile (R14 measured: MT=32 raised occupancy
                            // 52->86% but LOWERED BW 2.2->1.7TB/s; dur +35%. Edge is
                            // gather-BW-bound, not wave-starved. 64 is the optimum.)
#define STC    68           // col-major result tile stride in shorts (mult of 4 for b64)
#define NVPAD  132          // node f32 result tile stride in floats (128+4)
#define NB_SCAN ((NNODES + 255) / 256)   // 391
#define NB_HIST ((NEDGES + 255) / 256)   // 2500
#define NB_PREP (((KA + KB) * WIDTH + 255) / 256)  // 224

typedef __attribute__((ext_vector_type(8))) short short8;
typedef __attribute__((ext_vector_type(4))) short short4v;
typedef __attribute__((ext_vector_type(4))) float floatx4;

// round-to-nearest-even float->bf16 (used once, for weights)
__device__ __forceinline__ short f2bf_rne(float f) {
    unsigned u = __float_as_uint(f);
    unsigned r = u + 0x7fffu + ((u >> 16) & 1u);
    return (short)(r >> 16);
}
// truncating float->bf16 (cheap, staging only; <=1ulp err)
__device__ __forceinline__ short f2bf_t(float f) {
    return (short)(__float_as_uint(f) >> 16);
}
__device__ __forceinline__ float bf2f(short s) {
    return __uint_as_float(((unsigned)(unsigned short)s) << 16);
}
// order-preserving float<->unsigned; encu(x) > 0 for all non-(-NaN) floats,
// so 0x00000000 (memset) is the "empty segment" sentinel
__device__ __forceinline__ unsigned encu(float f) {
    unsigned u = __float_as_uint(f);
    return (u & 0x80000000u) ? ~u : (u | 0x80000000u);
}
__device__ __forceinline__ float decu(unsigned e) {
    unsigned u = (e & 0x80000000u) ? (e ^ 0x80000000u) : ~e;
    return __uint_as_float(u);
}

// ---------------------------------------------------------------------------
// fused: hist (blocks [0, NB_HIST)) + weight prep (blocks [NB_HIST, ...))
// ---------------------------------------------------------------------------
__global__ __launch_bounds__(256) void prep_hist_kernel(
    const int* __restrict__ e, int* __restrict__ counts,
    const float* __restrict__ W_edge, const float* __restrict__ W_mlp,
    short* __restrict__ We_t, short* __restrict__ Wm_t)
{
    int b = blockIdx.x;
    if (b < NB_HIST) {
        int i = b * 256 + threadIdx.x;
        if (i < NEDGES) atomicAdd(&counts[e[NEDGES + i]], 1);
    } else {
        int t = (b - NB_HIST) * 256 + threadIdx.x;
        if (t < KA * WIDTH) {
            int k = t / WIDTH, n = t % WIDTH;
            We_t[n * KA + k] = f2bf_rne(W_edge[t]);
        } else if (t < (KA + KB) * WIDTH) {
            int j = t - KA * WIDTH;
            int k = j / WIDTH, n = j % WIDTH;
            Wm_t[n * KB + k] = f2bf_rne(W_mlp[j]);
        }
    }
}

// ---------------------------------------------------------------------------
// fused scan (R16): per-block exclusive scan of counts; the LAST finishing
// block (device atomic ticket) performs the top-level scan of blockSum.
// blockSum reads in the last block use atomicAdd(p,0) to bypass potentially
// stale caches (per-XCD L2 non-coherence, G16).
// ---------------------------------------------------------------------------
__global__ __launch_bounds__(256) void scan_kernel(
    const int* __restrict__ counts, int* __restrict__ cursor,
    int* __restrict__ blockSum, int* __restrict__ blockOff,
    int* __restrict__ ticket)
{
    __shared__ int s[256];
    __shared__ int bs[512];
    __shared__ bool isLast;
    int tid = threadIdx.x;
    int n = blockIdx.x * 256 + tid;
    int c = (n < NNODES) ? counts[n] : 0;
    s[tid] = c;
    __syncthreads();
    for (int off = 1; off < 256; off <<= 1) {
        int v = (tid >= off) ? s[tid - off] : 0;
        __syncthreads();
        s[tid] += v;
        __syncthreads();
    }
    if (n < NNODES) cursor[n] = s[tid] - c;     // exclusive within block
    if (tid == 255) {
        blockSum[blockIdx.x] = s[255];
        __threadfence();                        // publish before ticket
        int t = atomicAdd(ticket, 1);
        isLast = (t == (int)gridDim.x - 1);
    }
    __syncthreads();
    if (!isLast) return;

    // last block: scan NB_SCAN (391) block sums with 256 threads / 512 slots
    int v0 = (tid < NB_SCAN) ? atomicAdd(&blockSum[tid], 0) : 0;
    int v1 = (256 + tid < NB_SCAN) ? atomicAdd(&blockSum[256 + tid], 0) : 0;
    bs[tid] = v0; bs[256 + tid] = v1;
    __syncthreads();
    for (int off = 1; off < 512; off <<= 1) {
        int a = (tid >= off) ? bs[tid - off] : 0;
        int b = (256 + tid >= off) ? bs[256 + tid - off] : 0;
        __syncthreads();
        bs[tid] += a; bs[256 + tid] += b;
        __syncthreads();
    }
    if (tid < NB_SCAN) blockOff[tid] = bs[tid] - v0;            // exclusive
    if (256 + tid < NB_SCAN) blockOff[256 + tid] = bs[256 + tid] - v1;
}

// ---------------------------------------------------------------------------
// scatter (R16): single 16B store per edge (src,dst,eid,0) instead of
// separate 8B pSD + 4B pEid stores (halves random-write transactions)
// ---------------------------------------------------------------------------
__global__ __launch_bounds__(256) void scatter_kernel(
    const int* __restrict__ e, int* __restrict__ cursor,
    const int* __restrict__ blockOff, uint4* __restrict__ pE)
{
    int i = blockIdx.x * 256 + threadIdx.x;
    if (i < NEDGES) {
        int s = e[i];
        int d = e[NEDGES + i];
        int p = atomicAdd(&cursor[d], 1) + blockOff[d >> 8];
        pE[p] = make_uint4((unsigned)s, (unsigned)d, (unsigned)i, 0u);
    }
}

// ---------------------------------------------------------------------------
// edge (dst-sorted): ef = diffs + relu([diffs,e_feat] @ W_edge + b); in-LDS
// segmented max over dst-runs; plain store for tile-exclusive runs, atomicMax
// only at tile boundaries.  == R8 measured-best: 145.5us, 2.2TB/s ==
// Staging: stride-8 rows (independent dsts) with 4-deep batched issue.
// launch_bounds(256,4): bounds=6 forced spills (R1); MT=32 regressed (R14).
// R16: edge list is packed uint4 (broadcast loads; cost unchanged).
// ---------------------------------------------------------------------------
__global__ __launch_bounds__(256, 4) void edge_kernel(
    const float* __restrict__ x, const float* __restrict__ e_feat,
    const short* __restrict__ We_t, const float* __restrict__ b_edge,
    const uint4* __restrict__ pE, unsigned* __restrict__ mEnc)
{
    __shared__ __align__(16) short sA[MT * KA_PAD];   // staging; reused as col-major bf16 result tile
    __shared__ float sBias[WIDTH];
    __shared__ int   sDst[MT];
    __shared__ int   sHeadRow[MT + 1];
    __shared__ int   sMeta[3];          // nheads, prevSame, nextSame

    const int tid = threadIdx.x;
    if (tid < WIDTH) sBias[tid] = b_edge[tid];

    const int e0 = blockIdx.x * MT;
    const float4* xf4 = (const float4*)x;
    const float4* ef4 = (const float4*)e_feat;

    // ---- stage A = [bf16(diffs) | bf16(e_feat)], 4-deep batched issue ----
    {
        int mq = tid >> 5, c = tid & 31;
        uint4 sd[8];
        #pragma unroll
        for (int j = 0; j < 8; ++j) sd[j] = pE[e0 + mq + 8 * j];
        if (c == 0) {
            #pragma unroll
            for (int j = 0; j < 8; ++j) sDst[mq + 8 * j] = (int)sd[j].y;
        }
        #pragma unroll
        for (int half = 0; half < 2; ++half) {
            float4 xs[4], xd[4];
            #pragma unroll
            for (int j = 0; j < 4; ++j) {
                xs[j] = xf4[(size_t)sd[half * 4 + j].x * 32 + c];
                xd[j] = xf4[(size_t)sd[half * 4 + j].y * 32 + c];
            }
            #pragma unroll
            for (int j = 0; j < 4; ++j) {
                int mm = mq + 8 * (half * 4 + j);
                short4v df;
                df.x = f2bf_t(xd[j].x - xs[j].x);
                df.y = f2bf_t(xd[j].y - xs[j].y);
                df.z = f2bf_t(xd[j].z - xs[j].z);
                df.w = f2bf_t(xd[j].w - xs[j].w);
                *(short4v*)&sA[mm * KA_PAD + c * 4] = df;
            }
        }
        int mq2 = tid >> 4, c2 = tid & 15;
        unsigned eid[4];
        #pragma unroll
        for (int j = 0; j < 4; ++j) eid[j] = pE[e0 + mq2 + 16 * j].z;
        float4 fv[4];
        #pragma unroll
        for (int j = 0; j < 4; ++j) fv[j] = ef4[(size_t)eid[j] * 16 + c2];
        #pragma unroll
        for (int j = 0; j < 4; ++j) {
            int mm = mq2 + 16 * j;
            short4v sv;
            sv.x = f2bf_t(fv[j].x); sv.y = f2bf_t(fv[j].y);
            sv.z = f2bf_t(fv[j].z); sv.w = f2bf_t(fv[j].w);
            *(short4v*)&sA[mm * KA_PAD + WIDTH + c2 * 4] = sv;
        }
    }
    __syncthreads();

    // ---- run-head detection (wave 0) ----
    if (tid < 64) {
        bool head = (tid == 0) || (sDst[tid] != sDst[tid - 1]);
        unsigned long long mask = __ballot(head);
        int rank = __popcll(mask & ((1ull << tid) - 1ull));
        if (head) sHeadRow[rank] = tid;
        if (tid == 0) {
            int nh = (int)__popcll(mask);
            sMeta[0] = nh;
            sHeadRow[nh] = MT;
            int prevSame = 0, nextSame = 0;
            if (e0 > 0)           prevSame = (pE[e0 - 1].y  == (unsigned)sDst[0]);
            if (e0 + MT < NEDGES) nextSame = (pE[e0 + MT].y == (unsigned)sDst[MT - 1]);
            sMeta[1] = prevSame; sMeta[2] = nextSame;
        }
    }

    // ---- MFMA: 4 waves, wave w -> rows 0..63 x cols [w*32, w*32+32) ----
    const int wave = tid >> 6;
    const int lane = tid & 63;
    const int l15  = lane & 15;
    const int kq   = (lane >> 4) << 3;
    const int quad = lane >> 4;

    floatx4 acc[4][2];
    #pragma unroll
    for (int rt = 0; rt < 4; ++rt)
        #pragma unroll
        for (int ct = 0; ct < 2; ++ct)
            acc[rt][ct] = (floatx4){0.f, 0.f, 0.f, 0.f};

    #pragma unroll
    for (int kc = 0; kc < 6; ++kc) {
        int k0 = kc * 32 + kq;
        short8 a[4];
        #pragma unroll
        for (int rt = 0; rt < 4; ++rt)
            a[rt] = *(const short8*)&sA[(rt * 16 + l15) * KA_PAD + k0];
        short8 b[2];
        #pragma unroll
        for (int ct = 0; ct < 2; ++ct)
            b[ct] = *(const short8*)&We_t[(size_t)(wave * 32 + ct * 16 + l15) * KA + k0];
        #pragma unroll
        for (int rt = 0; rt < 4; ++rt)
            #pragma unroll
            for (int ct = 0; ct < 2; ++ct)
                acc[rt][ct] = __builtin_amdgcn_mfma_f32_16x16x32_bf16(a[rt], b[ct], acc[rt][ct], 0, 0, 0);
    }

    // ---- ef = resid + relu(acc + bias) ----
    #pragma unroll
    for (int rt = 0; rt < 4; ++rt) {
        #pragma unroll
        for (int ct = 0; ct < 2; ++ct) {
            int col = wave * 32 + ct * 16 + l15;
            float bias = sBias[col];
            #pragma unroll
            for (int i = 0; i < 4; ++i) {
                int row = rt * 16 + quad * 4 + i;
                float v = acc[rt][ct][i] + bias;
                v = v > 0.f ? v : 0.f;
                acc[rt][ct][i] = v + bf2f(sA[row * KA_PAD + col]);
            }
        }
    }
    __syncthreads();   // sA reads done; sHeadRow/sMeta published

    // ---- write bf16 result tile COL-MAJOR (stride STC shorts): a lane's 4
    //      accumulator rows are contiguous -> single ds_write_b64
    short* sT = sA;
    #pragma unroll
    for (int rt = 0; rt < 4; ++rt) {
        #pragma unroll
        for (int ct = 0; ct < 2; ++ct) {
            int col = wave * 32 + ct * 16 + l15;
            short4v pk;
            pk.x = f2bf_t(acc[rt][ct][0]);
            pk.y = f2bf_t(acc[rt][ct][1]);
            pk.z = f2bf_t(acc[rt][ct][2]);
            pk.w = f2bf_t(acc[rt][ct][3]);
            *(short4v*)&sT[col * STC + rt * 16 + quad * 4] = pk;
        }
    }
    __syncthreads();

    // ---- segmented max over runs: per (run, col) item, walk the column's
    //      contiguous rows as b32 words (2 rows/read) ----
    const int nh = sMeta[0], prevSame = sMeta[1], nextSame = sMeta[2];
    const unsigned* sT32 = (const unsigned*)sT;
    for (int p = tid; p < (nh << 7); p += 256) {
        int h = p >> 7, c = p & 127;
        int r0 = sHeadRow[h], r1 = sHeadRow[h + 1];
        const unsigned* colp = sT32 + c * (STC / 2);
        int w0 = r0 >> 1, w1 = (r1 - 1) >> 1;
        float m = -3.4e38f;
        for (int w = w0; w <= w1; ++w) {
            unsigned u = colp[w];
            float flo = bf2f((short)(u & 0xffffu));
            float fhi = bf2f((short)(u >> 16));
            if (2 * w >= r0)    m = fmaxf(m, flo);
            if (2 * w + 1 < r1) m = fmaxf(m, fhi);
        }
        int dst = sDst[r0];
        unsigned ev = encu(m);
        unsigned* dp = &mEnc[(size_t)dst * WIDTH + c];
        bool atom = (h == 0 && prevSame) || (h == nh - 1 && nextSame);
        if (atom) atomicMax(dp, ev);
        else      *dp = ev;
    }
}

// ---------------------------------------------------------------------------
// node: out = x + relu([x, maxes] @ W_mlp + b_mlp)
// R15: epilogue via f32 LDS tile (reuses sA) -> coalesced float4 epilogue.
// ---------------------------------------------------------------------------
__global__ __launch_bounds__(256) void node_kernel(
    const float* __restrict__ x, const short* __restrict__ Wm_t,
    const float* __restrict__ b_mlp, float* __restrict__ out)
{
    __shared__ __align__(16) short sA[MT * KB_PAD];   // staging; reused as f32 [64][NVPAD] result tile
    __shared__ float sBias[WIDTH];

    const int tid = threadIdx.x;
    if (tid < WIDTH) sBias[tid] = b_mlp[tid];

    const int n0 = blockIdx.x * MT;
    const float4* xf4 = (const float4*)x;
    const uint4* enc4 = (const uint4*)out;

    {
        int mq = tid >> 5, c = tid & 31;
        #pragma unroll
        for (int mm = mq; mm < MT; mm += 8) {
            int node = n0 + mm;
            if (node >= NNODES) node = NNODES - 1;
            float4 xv = xf4[(size_t)node * 32 + c];
            short4v sx;
            sx.x = f2bf_rne(xv.x); sx.y = f2bf_rne(xv.y);
            sx.z = f2bf_rne(xv.z); sx.w = f2bf_rne(xv.w);
            *(short4v*)&sA[mm * KB_PAD + c * 4] = sx;
            uint4 ev = enc4[(size_t)node * 32 + c];
            short4v sm;
            sm.x = f2bf_rne(ev.x == 0u ? 0.f : decu(ev.x));
            sm.y = f2bf_rne(ev.y == 0u ? 0.f : decu(ev.y));
            sm.z = f2bf_rne(ev.z == 0u ? 0.f : decu(ev.z));
            sm.w = f2bf_rne(ev.w == 0u ? 0.f : decu(ev.w));
            *(short4v*)&sA[mm * KB_PAD + WIDTH + c * 4] = sm;
        }
    }
    __syncthreads();

    const int wave = tid >> 6;
    const int lane = tid & 63;
    const int l15  = lane & 15;
    const int kq   = (lane >> 4) << 3;
    const int quad = lane >> 4;

    floatx4 acc[4][2];
    #pragma unroll
    for (int rt = 0; rt < 4; ++rt)
        #pragma unroll
        for (int ct = 0; ct < 2; ++ct)
            acc[rt][ct] = (floatx4){0.f, 0.f, 0.f, 0.f};

    #pragma unroll
    for (int kc = 0; kc < 8; ++kc) {
        int k0 = kc * 32 + kq;
        short8 a[4];
        #pragma unroll
        for (int rt = 0; rt < 4; ++rt)
            a[rt] = *(const short8*)&sA[(rt * 16 + l15) * KB_PAD + k0];
        short8 b[2];
        #pragma unroll
        for (int ct = 0; ct < 2; ++ct)
            b[ct] = *(const short8*)&Wm_t[(size_t)(wave * 32 + ct * 16 + l15) * KB + k0];
        #pragma unroll
        for (int rt = 0; rt < 4; ++rt)
            #pragma unroll
            for (int ct = 0; ct < 2; ++ct)
                acc[rt][ct] = __builtin_amdgcn_mfma_f32_16x16x32_bf16(a[rt], b[ct], acc[rt][ct], 0, 0, 0);
    }
    __syncthreads();   // staging reads done; sA reused as f32 tile

    // ---- v = relu(acc + bias) -> LDS f32 tile [MT][NVPAD] ----
    float* sV = (float*)sA;
    #pragma unroll
    for (int rt = 0; rt < 4; ++rt) {
        #pragma unroll
        for (int ct = 0; ct < 2; ++ct) {
            int col = wave * 32 + ct * 16 + l15;
            float bias = sBias[col];
            #pragma unroll
            for (int i = 0; i < 4; ++i) {
                int row = rt * 16 + quad * 4 + i;
                float v = acc[rt][ct][i] + bias;
                sV[row * NVPAD + col] = v > 0.f ? v : 0.f;
            }
        }
    }
    __syncthreads();

    // ---- coalesced epilogue: out = x + v, float4 per lane ----
    {
        int q = tid & 31, r0 = tid >> 5;
        #pragma unroll
        for (int pass = 0; pass < 8; ++pass) {
            int r = r0 + 8 * pass;
            int node = n0 + r;
            if (node < NNODES) {
                float4 xv = xf4[(size_t)node * 32 + q];
                const float* vp = &sV[r * NVPAD + q * 4];
                float4 ov;
                ov.x = xv.x + vp[0];
                ov.y = xv.y + vp[1];
                ov.z = xv.z + vp[2];
                ov.w = xv.w + vp[3];
                ((float4*)out)[(size_t)node * 32 + q] = ov;
            }
        }
    }
}

extern "C" void kernel_launch(void* const* d_in, const int* in_sizes, int n_in,
                              void* d_out, int out_size, void* d_ws, size_t ws_size,
                              hipStream_t stream) {
    const float* x      = (const float*)d_in[0];
    const int*   e      = (const int*)d_in[1];
    const float* e_feat = (const float*)d_in[2];
    const float* W_edge = (const float*)d_in[3];
    const float* b_edge = (const float*)d_in[4];
    const float* W_mlp  = (const float*)d_in[5];
    const float* b_mlp  = (const float*)d_in[6];
    float*    out  = (float*)d_out;
    unsigned* mEnc = (unsigned*)d_out;           // segment-max lives in d_out

    short* We_t = (short*)d_ws;                           // [128][192] bf16
    short* Wm_t = We_t + (size_t)KA * WIDTH;              // [128][256] bf16
    uint4* pE   = (uint4*)((char*)d_ws + 114688);         // [E] (src,dst,eid,0) 16B-aligned
    int* counts   = (int*)(pE + NEDGES);                  // [N]
    int* ticket   = counts + NNODES;                      // [1] (zeroed with counts)
    int* cursor   = ticket + 1;                           // [N]
    int* blockSum = cursor + NNODES;                      // [NB_SCAN]
    int* blockOff = blockSum + NB_SCAN;                   // [NB_SCAN]

    hipMemsetAsync(d_out, 0, (size_t)NNODES * WIDTH * 4, stream);   // empty = enc 0
    hipMemsetAsync(counts, 0, (size_t)(NNODES + 1) * 4, stream);    // counts + ticket
    prep_hist_kernel<<<NB_HIST + NB_PREP, 256, 0, stream>>>(e, counts, W_edge, W_mlp, We_t, Wm_t);
    scan_kernel<<<NB_SCAN, 256, 0, stream>>>(counts, cursor, blockSum, blockOff, ticket);
    scatter_kernel<<<(NEDGES + 255) / 256, 256, 0, stream>>>(e, cursor, blockOff, pE);
    edge_kernel<<<NEDGES / MT, 256, 0, stream>>>(x, e_feat, We_t, b_edge, pE, mEnc);
    node_kernel<<<(NNODES + MT - 1) / MT, 256, 0, stream>>>(x, Wm_t, b_mlp, out);
}

// Round 17
// 463.894 us; speedup vs baseline: 1.0260x; 1.0260x over previous
//
#include <hip/hip_runtime.h>
#include <hip/hip_bf16.h>
#include <limits.h>

#define NNODES 100000
#define NEDGES 640000
#define WIDTH  128
#define NFEAT  64
#define KA     192          // edge GEMM K (128 diffs + 64 e_feat)
#define KA_PAD 196          // LDS row stride (bf16): 98 words, %32==2 -> 2-way (free)
                            // measured: 1.48M conflicts vs 5.3M at pad=200 (R1 vs R2)
#define KB     256          // node GEMM K (128 x + 128 maxes)
#define KB_PAD 264
#define MT     64           // rows per tile (R14 measured: MT=32 raised occupancy
                            // 52->86% but LOWERED BW 2.2->1.7TB/s; dur +35%. Edge is
                            // gather-BW-bound, not wave-starved. 64 is the optimum.)
#define STC    68           // col-major result tile stride in shorts (mult of 4 for b64)
#define NVPAD  132          // node f32 result tile stride in floats (128+4)
#define NB_SCAN ((NNODES + 255) / 256)   // 391
#define NB_HIST ((NEDGES + 255) / 256)   // 2500
#define NB_PREP (((KA + KB) * WIDTH + 255) / 256)  // 224

typedef __attribute__((ext_vector_type(8))) short short8;
typedef __attribute__((ext_vector_type(4))) short short4v;
typedef __attribute__((ext_vector_type(4))) float floatx4;

// round-to-nearest-even float->bf16 (used once, for weights)
__device__ __forceinline__ short f2bf_rne(float f) {
    unsigned u = __float_as_uint(f);
    unsigned r = u + 0x7fffu + ((u >> 16) & 1u);
    return (short)(r >> 16);
}
// truncating float->bf16 (cheap, staging only; <=1ulp err)
__device__ __forceinline__ short f2bf_t(float f) {
    return (short)(__float_as_uint(f) >> 16);
}
__device__ __forceinline__ float bf2f(short s) {
    return __uint_as_float(((unsigned)(unsigned short)s) << 16);
}
// order-preserving float<->unsigned; encu(x) > 0 for all non-(-NaN) floats,
// so 0x00000000 (memset) is the "empty segment" sentinel
__device__ __forceinline__ unsigned encu(float f) {
    unsigned u = __float_as_uint(f);
    return (u & 0x80000000u) ? ~u : (u | 0x80000000u);
}
__device__ __forceinline__ float decu(unsigned e) {
    unsigned u = (e & 0x80000000u) ? (e ^ 0x80000000u) : ~e;
    return __uint_as_float(u);
}

// ---------------------------------------------------------------------------
// fused: hist (blocks [0, NB_HIST)) + weight prep (blocks [NB_HIST, ...))
// ---------------------------------------------------------------------------
__global__ __launch_bounds__(256) void prep_hist_kernel(
    const int* __restrict__ e, int* __restrict__ counts,
    const float* __restrict__ W_edge, const float* __restrict__ W_mlp,
    short* __restrict__ We_t, short* __restrict__ Wm_t)
{
    int b = blockIdx.x;
    if (b < NB_HIST) {
        int i = b * 256 + threadIdx.x;
        if (i < NEDGES) atomicAdd(&counts[e[NEDGES + i]], 1);
    } else {
        int t = (b - NB_HIST) * 256 + threadIdx.x;
        if (t < KA * WIDTH) {
            int k = t / WIDTH, n = t % WIDTH;
            We_t[n * KA + k] = f2bf_rne(W_edge[t]);
        } else if (t < (KA + KB) * WIDTH) {
            int j = t - KA * WIDTH;
            int k = j / WIDTH, n = j % WIDTH;
            Wm_t[n * KB + k] = f2bf_rne(W_mlp[j]);
        }
    }
}

// ---------------------------------------------------------------------------
// counting sort by dst: hist -> scanA -> scanB -> scatter (R15 structure;
// R16's ticket-fused scan + uint4 pack measured +7.7us -> reverted)
// ---------------------------------------------------------------------------
__global__ __launch_bounds__(256) void scanA_kernel(
    const int* __restrict__ counts, int* __restrict__ cursor, int* __restrict__ blockSum)
{
    __shared__ int s[256];
    int tid = threadIdx.x;
    int n = blockIdx.x * 256 + tid;
    int c = (n < NNODES) ? counts[n] : 0;
    s[tid] = c;
    __syncthreads();
    for (int off = 1; off < 256; off <<= 1) {
        int v = (tid >= off) ? s[tid - off] : 0;
        __syncthreads();
        s[tid] += v;
        __syncthreads();
    }
    if (n < NNODES) cursor[n] = s[tid] - c;     // exclusive within block
    if (tid == 255) blockSum[blockIdx.x] = s[255];
}

__global__ __launch_bounds__(512) void scanB_kernel(int* __restrict__ blockSum,
                                                    int* __restrict__ blockOff)
{
    __shared__ int s[512];
    int tid = threadIdx.x;
    int c = (tid < NB_SCAN) ? blockSum[tid] : 0;
    s[tid] = c;
    __syncthreads();
    for (int off = 1; off < 512; off <<= 1) {
        int v = (tid >= off) ? s[tid - off] : 0;
        __syncthreads();
        s[tid] += v;
        __syncthreads();
    }
    if (tid < NB_SCAN) blockOff[tid] = s[tid] - c;  // exclusive
}

__global__ __launch_bounds__(256) void scatter_kernel(
    const int* __restrict__ e, int* __restrict__ cursor,
    const int* __restrict__ blockOff,
    uint2* __restrict__ pSD, int* __restrict__ pEid)
{
    int i = blockIdx.x * 256 + threadIdx.x;
    if (i < NEDGES) {
        int s = e[i];
        int d = e[NEDGES + i];
        int p = atomicAdd(&cursor[d], 1) + blockOff[d >> 8];
        pSD[p] = make_uint2((unsigned)s, (unsigned)d);
        pEid[p] = i;
    }
}

// ---------------------------------------------------------------------------
// edge (dst-sorted): ef = diffs + relu([diffs,e_feat] @ W_edge + b); in-LDS
// segmented max over dst-runs; plain store for tile-exclusive runs, atomicMax
// only at tile boundaries.  == R8/R15 measured-best: 145.5us, 2.2TB/s ==
// Staging: stride-8 rows (independent dsts) with 4-deep batched issue.
// launch_bounds(256,4): bounds=6 forced spills (R1); MT=32 regressed (R14).
// ---------------------------------------------------------------------------
__global__ __launch_bounds__(256, 4) void edge_kernel(
    const float* __restrict__ x, const float* __restrict__ e_feat,
    const short* __restrict__ We_t, const float* __restrict__ b_edge,
    const uint2* __restrict__ pSD, const int* __restrict__ pEid,
    unsigned* __restrict__ mEnc)
{
    __shared__ __align__(16) short sA[MT * KA_PAD];   // staging; reused as col-major bf16 result tile
    __shared__ float sBias[WIDTH];
    __shared__ int   sDst[MT];
    __shared__ int   sHeadRow[MT + 1];
    __shared__ int   sMeta[3];          // nheads, prevSame, nextSame

    const int tid = threadIdx.x;
    if (tid < WIDTH) sBias[tid] = b_edge[tid];

    const int e0 = blockIdx.x * MT;
    const float4* xf4 = (const float4*)x;
    const float4* ef4 = (const float4*)e_feat;

    // ---- stage A = [bf16(diffs) | bf16(e_feat)], 4-deep batched issue ----
    {
        int mq = tid >> 5, c = tid & 31;
        uint2 sd[8];
        #pragma unroll
        for (int j = 0; j < 8; ++j) sd[j] = pSD[e0 + mq + 8 * j];
        if (c == 0) {
            #pragma unroll
            for (int j = 0; j < 8; ++j) sDst[mq + 8 * j] = (int)sd[j].y;
        }
        #pragma unroll
        for (int half = 0; half < 2; ++half) {
            float4 xs[4], xd[4];
            #pragma unroll
            for (int j = 0; j < 4; ++j) {
                xs[j] = xf4[(size_t)sd[half * 4 + j].x * 32 + c];
                xd[j] = xf4[(size_t)sd[half * 4 + j].y * 32 + c];
            }
            #pragma unroll
            for (int j = 0; j < 4; ++j) {
                int mm = mq + 8 * (half * 4 + j);
                short4v df;
                df.x = f2bf_t(xd[j].x - xs[j].x);
                df.y = f2bf_t(xd[j].y - xs[j].y);
                df.z = f2bf_t(xd[j].z - xs[j].z);
                df.w = f2bf_t(xd[j].w - xs[j].w);
                *(short4v*)&sA[mm * KA_PAD + c * 4] = df;
            }
        }
        int mq2 = tid >> 4, c2 = tid & 15;
        int eid[4];
        #pragma unroll
        for (int j = 0; j < 4; ++j) eid[j] = pEid[e0 + mq2 + 16 * j];
        float4 fv[4];
        #pragma unroll
        for (int j = 0; j < 4; ++j) fv[j] = ef4[(size_t)eid[j] * 16 + c2];
        #pragma unroll
        for (int j = 0; j < 4; ++j) {
            int mm = mq2 + 16 * j;
            short4v sv;
            sv.x = f2bf_t(fv[j].x); sv.y = f2bf_t(fv[j].y);
            sv.z = f2bf_t(fv[j].z); sv.w = f2bf_t(fv[j].w);
            *(short4v*)&sA[mm * KA_PAD + WIDTH + c2 * 4] = sv;
        }
    }
    __syncthreads();

    // ---- run-head detection (wave 0) ----
    if (tid < 64) {
        bool head = (tid == 0) || (sDst[tid] != sDst[tid - 1]);
        unsigned long long mask = __ballot(head);
        int rank = __popcll(mask & ((1ull << tid) - 1ull));
        if (head) sHeadRow[rank] = tid;
        if (tid == 0) {
            int nh = (int)__popcll(mask);
            sMeta[0] = nh;
            sHeadRow[nh] = MT;
            int prevSame = 0, nextSame = 0;
            if (e0 > 0)           prevSame = (pSD[e0 - 1].y  == (unsigned)sDst[0]);
            if (e0 + MT < NEDGES) nextSame = (pSD[e0 + MT].y == (unsigned)sDst[MT - 1]);
            sMeta[1] = prevSame; sMeta[2] = nextSame;
        }
    }

    // ---- MFMA: 4 waves, wave w -> rows 0..63 x cols [w*32, w*32+32) ----
    const int wave = tid >> 6;
    const int lane = tid & 63;
    const int l15  = lane & 15;
    const int kq   = (lane >> 4) << 3;
    const int quad = lane >> 4;

    floatx4 acc[4][2];
    #pragma unroll
    for (int rt = 0; rt < 4; ++rt)
        #pragma unroll
        for (int ct = 0; ct < 2; ++ct)
            acc[rt][ct] = (floatx4){0.f, 0.f, 0.f, 0.f};

    #pragma unroll
    for (int kc = 0; kc < 6; ++kc) {
        int k0 = kc * 32 + kq;
        short8 a[4];
        #pragma unroll
        for (int rt = 0; rt < 4; ++rt)
            a[rt] = *(const short8*)&sA[(rt * 16 + l15) * KA_PAD + k0];
        short8 b[2];
        #pragma unroll
        for (int ct = 0; ct < 2; ++ct)
            b[ct] = *(const short8*)&We_t[(size_t)(wave * 32 + ct * 16 + l15) * KA + k0];
        #pragma unroll
        for (int rt = 0; rt < 4; ++rt)
            #pragma unroll
            for (int ct = 0; ct < 2; ++ct)
                acc[rt][ct] = __builtin_amdgcn_mfma_f32_16x16x32_bf16(a[rt], b[ct], acc[rt][ct], 0, 0, 0);
    }

    // ---- ef = resid + relu(acc + bias) ----
    #pragma unroll
    for (int rt = 0; rt < 4; ++rt) {
        #pragma unroll
        for (int ct = 0; ct < 2; ++ct) {
            int col = wave * 32 + ct * 16 + l15;
            float bias = sBias[col];
            #pragma unroll
            for (int i = 0; i < 4; ++i) {
                int row = rt * 16 + quad * 4 + i;
                float v = acc[rt][ct][i] + bias;
                v = v > 0.f ? v : 0.f;
                acc[rt][ct][i] = v + bf2f(sA[row * KA_PAD + col]);
            }
        }
    }
    __syncthreads();   // sA reads done; sHeadRow/sMeta published

    // ---- write bf16 result tile COL-MAJOR (stride STC shorts): a lane's 4
    //      accumulator rows are contiguous -> single ds_write_b64
    short* sT = sA;
    #pragma unroll
    for (int rt = 0; rt < 4; ++rt) {
        #pragma unroll
        for (int ct = 0; ct < 2; ++ct) {
            int col = wave * 32 + ct * 16 + l15;
            short4v pk;
            pk.x = f2bf_t(acc[rt][ct][0]);
            pk.y = f2bf_t(acc[rt][ct][1]);
            pk.z = f2bf_t(acc[rt][ct][2]);
            pk.w = f2bf_t(acc[rt][ct][3]);
            *(short4v*)&sT[col * STC + rt * 16 + quad * 4] = pk;
        }
    }
    __syncthreads();

    // ---- segmented max over runs: per (run, col) item, walk the column's
    //      contiguous rows as b32 words (2 rows/read) ----
    const int nh = sMeta[0], prevSame = sMeta[1], nextSame = sMeta[2];
    const unsigned* sT32 = (const unsigned*)sT;
    for (int p = tid; p < (nh << 7); p += 256) {
        int h = p >> 7, c = p & 127;
        int r0 = sHeadRow[h], r1 = sHeadRow[h + 1];
        const unsigned* colp = sT32 + c * (STC / 2);
        int w0 = r0 >> 1, w1 = (r1 - 1) >> 1;
        float m = -3.4e38f;
        for (int w = w0; w <= w1; ++w) {
            unsigned u = colp[w];
            float flo = bf2f((short)(u & 0xffffu));
            float fhi = bf2f((short)(u >> 16));
            if (2 * w >= r0)    m = fmaxf(m, flo);
            if (2 * w + 1 < r1) m = fmaxf(m, fhi);
        }
        int dst = sDst[r0];
        unsigned ev = encu(m);
        unsigned* dp = &mEnc[(size_t)dst * WIDTH + c];
        bool atom = (h == 0 && prevSame) || (h == nh - 1 && nextSame);
        if (atom) atomicMax(dp, ev);
        else      *dp = ev;
    }
}

// ---------------------------------------------------------------------------
// node: out = x + relu([x, maxes] @ W_mlp + b_mlp)
// R15: coalesced float4 epilogue via f32 LDS tile (reuses sA).
// R17: x float4s kept in registers from staging (same (row,col4) thread
// mapping) -> second 51.2MB x-read deleted; node traffic 205->154MB.
// ---------------------------------------------------------------------------
__global__ __launch_bounds__(256) void node_kernel(
    const float* __restrict__ x, const short* __restrict__ Wm_t,
    const float* __restrict__ b_mlp, float* __restrict__ out)
{
    __shared__ __align__(16) short sA[MT * KB_PAD];   // staging; reused as f32 [64][NVPAD] result tile
    __shared__ float sBias[WIDTH];

    const int tid = threadIdx.x;
    if (tid < WIDTH) sBias[tid] = b_mlp[tid];

    const int n0 = blockIdx.x * MT;
    const float4* xf4 = (const float4*)x;
    const uint4* enc4 = (const uint4*)out;

    float4 xvs[8];                      // R17: staged x rows, reused in epilogue
    {
        int mq = tid >> 5, c = tid & 31;
        #pragma unroll
        for (int j = 0; j < 8; ++j) {
            int mm = mq + 8 * j;
            int node = n0 + mm;
            if (node >= NNODES) node = NNODES - 1;
            float4 xv = xf4[(size_t)node * 32 + c];
            xvs[j] = xv;
            short4v sx;
            sx.x = f2bf_rne(xv.x); sx.y = f2bf_rne(xv.y);
            sx.z = f2bf_rne(xv.z); sx.w = f2bf_rne(xv.w);
            *(short4v*)&sA[mm * KB_PAD + c * 4] = sx;
            uint4 ev = enc4[(size_t)node * 32 + c];
            short4v sm;
            sm.x = f2bf_rne(ev.x == 0u ? 0.f : decu(ev.x));
            sm.y = f2bf_rne(ev.y == 0u ? 0.f : decu(ev.y));
            sm.z = f2bf_rne(ev.z == 0u ? 0.f : decu(ev.z));
            sm.w = f2bf_rne(ev.w == 0u ? 0.f : decu(ev.w));
            *(short4v*)&sA[mm * KB_PAD + WIDTH + c * 4] = sm;
        }
    }
    __syncthreads();

    const int wave = tid >> 6;
    const int lane = tid & 63;
    const int l15  = lane & 15;
    const int kq   = (lane >> 4) << 3;
    const int quad = lane >> 4;

    floatx4 acc[4][2];
    #pragma unroll
    for (int rt = 0; rt < 4; ++rt)
        #pragma unroll
        for (int ct = 0; ct < 2; ++ct)
            acc[rt][ct] = (floatx4){0.f, 0.f, 0.f, 0.f};

    #pragma unroll
    for (int kc = 0; kc < 8; ++kc) {
        int k0 = kc * 32 + kq;
        short8 a[4];
        #pragma unroll
        for (int rt = 0; rt < 4; ++rt)
            a[rt] = *(const short8*)&sA[(rt * 16 + l15) * KB_PAD + k0];
        short8 b[2];
        #pragma unroll
        for (int ct = 0; ct < 2; ++ct)
            b[ct] = *(const short8*)&Wm_t[(size_t)(wave * 32 + ct * 16 + l15) * KB + k0];
        #pragma unroll
        for (int rt = 0; rt < 4; ++rt)
            #pragma unroll
            for (int ct = 0; ct < 2; ++ct)
                acc[rt][ct] = __builtin_amdgcn_mfma_f32_16x16x32_bf16(a[rt], b[ct], acc[rt][ct], 0, 0, 0);
    }
    __syncthreads();   // staging reads done; sA reused as f32 tile

    // ---- v = relu(acc + bias) -> LDS f32 tile [MT][NVPAD] ----
    float* sV = (float*)sA;
    #pragma unroll
    for (int rt = 0; rt < 4; ++rt) {
        #pragma unroll
        for (int ct = 0; ct < 2; ++ct) {
            int col = wave * 32 + ct * 16 + l15;
            float bias = sBias[col];
            #pragma unroll
            for (int i = 0; i < 4; ++i) {
                int row = rt * 16 + quad * 4 + i;
                float v = acc[rt][ct][i] + bias;
                sV[row * NVPAD + col] = v > 0.f ? v : 0.f;
            }
        }
    }
    __syncthreads();

    // ---- coalesced epilogue: out = x + v, float4 per lane; x from registers
    {
        int q = tid & 31, r0 = tid >> 5;
        #pragma unroll
        for (int pass = 0; pass < 8; ++pass) {
            int r = r0 + 8 * pass;
            int node = n0 + r;
            if (node < NNODES) {
                float4 xv = xvs[pass];
                const float* vp = &sV[r * NVPAD + q * 4];
                float4 ov;
                ov.x = xv.x + vp[0];
                ov.y = xv.y + vp[1];
                ov.z = xv.z + vp[2];
                ov.w = xv.w + vp[3];
                ((float4*)out)[(size_t)node * 32 + q] = ov;
            }
        }
    }
}

extern "C" void kernel_launch(void* const* d_in, const int* in_sizes, int n_in,
                              void* d_out, int out_size, void* d_ws, size_t ws_size,
                              hipStream_t stream) {
    const float* x      = (const float*)d_in[0];
    const int*   e      = (const int*)d_in[1];
    const float* e_feat = (const float*)d_in[2];
    const float* W_edge = (const float*)d_in[3];
    const float* b_edge = (const float*)d_in[4];
    const float* W_mlp  = (const float*)d_in[5];
    const float* b_mlp  = (const float*)d_in[6];
    float*    out  = (float*)d_out;
    unsigned* mEnc = (unsigned*)d_out;           // segment-max lives in d_out

    short* We_t = (short*)d_ws;                           // [128][192] bf16
    short* Wm_t = We_t + (size_t)KA * WIDTH;              // [128][256] bf16
    int* base     = (int*)((char*)d_ws + 114688);         // 8B-aligned
    uint2* pSD    = (uint2*)base;                         // [E] (src,dst) sorted
    int* pEid     = (int*)(base + 2 * NEDGES);            // [E]
    int* counts   = pEid + NEDGES;                        // [N]
    int* cursor   = counts + NNODES;                      // [N]
    int* blockSum = cursor + NNODES;                      // [NB_SCAN]
    int* blockOff = blockSum + NB_SCAN;                   // [NB_SCAN]

    hipMemsetAsync(d_out, 0, (size_t)NNODES * WIDTH * 4, stream);   // empty = enc 0
    hipMemsetAsync(counts, 0, (size_t)NNODES * 4, stream);
    prep_hist_kernel<<<NB_HIST + NB_PREP, 256, 0, stream>>>(e, counts, W_edge, W_mlp, We_t, Wm_t);
    scanA_kernel<<<NB_SCAN, 256, 0, stream>>>(counts, cursor, blockSum);
    scanB_kernel<<<1, 512, 0, stream>>>(blockSum, blockOff);
    scatter_kernel<<<(NEDGES + 255) / 256, 256, 0, stream>>>(e, cursor, blockOff, pSD, pEid);
    edge_kernel<<<NEDGES / MT, 256, 0, stream>>>(x, e_feat, We_t, b_edge, pSD, pEid, mEnc);
    node_kernel<<<(NNODES + MT - 1) / MT, 256, 0, stream>>>(x, Wm_t, b_mlp, out);
}

// Round 18
// 462.091 us; speedup vs baseline: 1.0300x; 1.0039x over previous
//
#include <hip/hip_runtime.h>
#include <hip/hip_bf16.h>
#include <limits.h>

#define NNODES 100000
#define NEDGES 640000
#define WIDTH  128
#define NFEAT  64
#define KA     192          // edge GEMM K (128 diffs + 64 e_feat)
#define KA_PAD 196          // LDS row stride (bf16): 98 words, %32==2 -> 2-way (free)
                            // measured: 1.48M conflicts vs 5.3M at pad=200 (R1 vs R2)
#define KB     256          // node GEMM K (128 x + 128 maxes)
#define KB_PAD 264
#define MT     64           // rows per tile (R14 measured: MT=32 raised occupancy
                            // 52->86% but LOWERED BW 2.2->1.7TB/s; dur +35%. Edge is
                            // gather-BW-bound, not wave-starved. 64 is the optimum.)
#define STC    68           // col-major result tile stride in shorts (mult of 4 for b64)
#define NVPAD  132          // node f32 result tile stride in floats (128+4)
#define NB_SCAN ((NNODES + 255) / 256)   // 391
#define NB_HIST ((NEDGES + 255) / 256)   // 2500
#define NB_PREP (((KA + KB) * WIDTH + 255) / 256)  // 224

typedef __attribute__((ext_vector_type(8))) short short8;
typedef __attribute__((ext_vector_type(4))) short short4v;
typedef __attribute__((ext_vector_type(4))) float floatx4;

// round-to-nearest-even float->bf16 (used once, for weights)
__device__ __forceinline__ short f2bf_rne(float f) {
    unsigned u = __float_as_uint(f);
    unsigned r = u + 0x7fffu + ((u >> 16) & 1u);
    return (short)(r >> 16);
}
// truncating float->bf16 (cheap, staging only; <=1ulp err)
__device__ __forceinline__ short f2bf_t(float f) {
    return (short)(__float_as_uint(f) >> 16);
}
__device__ __forceinline__ float bf2f(short s) {
    return __uint_as_float(((unsigned)(unsigned short)s) << 16);
}
// order-preserving float<->unsigned; encu(x) > 0 for all non-(-NaN) floats,
// so 0x00000000 (memset) is the "empty segment" sentinel
__device__ __forceinline__ unsigned encu(float f) {
    unsigned u = __float_as_uint(f);
    return (u & 0x80000000u) ? ~u : (u | 0x80000000u);
}
__device__ __forceinline__ float decu(unsigned e) {
    unsigned u = (e & 0x80000000u) ? (e ^ 0x80000000u) : ~e;
    return __uint_as_float(u);
}

// ---------------------------------------------------------------------------
// fused: hist (blocks [0, NB_HIST)) + weight prep (blocks [NB_HIST, ...))
// ---------------------------------------------------------------------------
__global__ __launch_bounds__(256) void prep_hist_kernel(
    const int* __restrict__ e, int* __restrict__ counts,
    const float* __restrict__ W_edge, const float* __restrict__ W_mlp,
    short* __restrict__ We_t, short* __restrict__ Wm_t)
{
    int b = blockIdx.x;
    if (b < NB_HIST) {
        int i = b * 256 + threadIdx.x;
        if (i < NEDGES) atomicAdd(&counts[e[NEDGES + i]], 1);
    } else {
        int t = (b - NB_HIST) * 256 + threadIdx.x;
        if (t < KA * WIDTH) {
            int k = t / WIDTH, n = t % WIDTH;
            We_t[n * KA + k] = f2bf_rne(W_edge[t]);
        } else if (t < (KA + KB) * WIDTH) {
            int j = t - KA * WIDTH;
            int k = j / WIDTH, n = j % WIDTH;
            Wm_t[n * KB + k] = f2bf_rne(W_mlp[j]);
        }
    }
}

// ---------------------------------------------------------------------------
// counting sort by dst: hist -> scanA -> scanB -> scatter (R15 structure;
// R16's ticket-fused scan + uint4 pack measured +7.7us -> reverted)
// ---------------------------------------------------------------------------
__global__ __launch_bounds__(256) void scanA_kernel(
    const int* __restrict__ counts, int* __restrict__ cursor, int* __restrict__ blockSum)
{
    __shared__ int s[256];
    int tid = threadIdx.x;
    int n = blockIdx.x * 256 + tid;
    int c = (n < NNODES) ? counts[n] : 0;
    s[tid] = c;
    __syncthreads();
    for (int off = 1; off < 256; off <<= 1) {
        int v = (tid >= off) ? s[tid - off] : 0;
        __syncthreads();
        s[tid] += v;
        __syncthreads();
    }
    if (n < NNODES) cursor[n] = s[tid] - c;     // exclusive within block
    if (tid == 255) blockSum[blockIdx.x] = s[255];
}

__global__ __launch_bounds__(512) void scanB_kernel(int* __restrict__ blockSum,
                                                    int* __restrict__ blockOff)
{
    __shared__ int s[512];
    int tid = threadIdx.x;
    int c = (tid < NB_SCAN) ? blockSum[tid] : 0;
    s[tid] = c;
    __syncthreads();
    for (int off = 1; off < 512; off <<= 1) {
        int v = (tid >= off) ? s[tid - off] : 0;
        __syncthreads();
        s[tid] += v;
        __syncthreads();
    }
    if (tid < NB_SCAN) blockOff[tid] = s[tid] - c;  // exclusive
}

__global__ __launch_bounds__(256) void scatter_kernel(
    const int* __restrict__ e, int* __restrict__ cursor,
    const int* __restrict__ blockOff,
    uint2* __restrict__ pSD, int* __restrict__ pEid)
{
    int i = blockIdx.x * 256 + threadIdx.x;
    if (i < NEDGES) {
        int s = e[i];
        int d = e[NEDGES + i];
        int p = atomicAdd(&cursor[d], 1) + blockOff[d >> 8];
        pSD[p] = make_uint2((unsigned)s, (unsigned)d);
        pEid[p] = i;
    }
}

// ---------------------------------------------------------------------------
// edge (dst-sorted): ef = diffs + relu([diffs,e_feat] @ W_edge + b); in-LDS
// segmented max over dst-runs; plain store for tile-exclusive runs, atomicMax
// only at tile boundaries.  == R8/R15/R17 measured-best: 145.5us, 2.2TB/s ==
// Staging: stride-8 rows (independent dsts) with 4-deep batched issue.
// R18: launch_bounds(256,5) — R0-R2 ran 5 blocks/CU (occ 63%) at VGPR 40;
// R3+ dropped to 4 blocks at VGPR 44. Request min 5 waves/EU (reg cap ~102,
// current ~76-90 incl AGPR — fits; R1's bounds=6 at cap ~85 spilled).
// ---------------------------------------------------------------------------
__global__ __launch_bounds__(256, 5) void edge_kernel(
    const float* __restrict__ x, const float* __restrict__ e_feat,
    const short* __restrict__ We_t, const float* __restrict__ b_edge,
    const uint2* __restrict__ pSD, const int* __restrict__ pEid,
    unsigned* __restrict__ mEnc)
{
    __shared__ __align__(16) short sA[MT * KA_PAD];   // staging; reused as col-major bf16 result tile
    __shared__ float sBias[WIDTH];
    __shared__ int   sDst[MT];
    __shared__ int   sHeadRow[MT + 1];
    __shared__ int   sMeta[3];          // nheads, prevSame, nextSame

    const int tid = threadIdx.x;
    if (tid < WIDTH) sBias[tid] = b_edge[tid];

    const int e0 = blockIdx.x * MT;
    const float4* xf4 = (const float4*)x;
    const float4* ef4 = (const float4*)e_feat;

    // ---- stage A = [bf16(diffs) | bf16(e_feat)], 4-deep batched issue ----
    {
        int mq = tid >> 5, c = tid & 31;
        uint2 sd[8];
        #pragma unroll
        for (int j = 0; j < 8; ++j) sd[j] = pSD[e0 + mq + 8 * j];
        if (c == 0) {
            #pragma unroll
            for (int j = 0; j < 8; ++j) sDst[mq + 8 * j] = (int)sd[j].y;
        }
        #pragma unroll
        for (int half = 0; half < 2; ++half) {
            float4 xs[4], xd[4];
            #pragma unroll
            for (int j = 0; j < 4; ++j) {
                xs[j] = xf4[(size_t)sd[half * 4 + j].x * 32 + c];
                xd[j] = xf4[(size_t)sd[half * 4 + j].y * 32 + c];
            }
            #pragma unroll
            for (int j = 0; j < 4; ++j) {
                int mm = mq + 8 * (half * 4 + j);
                short4v df;
                df.x = f2bf_t(xd[j].x - xs[j].x);
                df.y = f2bf_t(xd[j].y - xs[j].y);
                df.z = f2bf_t(xd[j].z - xs[j].z);
                df.w = f2bf_t(xd[j].w - xs[j].w);
                *(short4v*)&sA[mm * KA_PAD + c * 4] = df;
            }
        }
        int mq2 = tid >> 4, c2 = tid & 15;
        int eid[4];
        #pragma unroll
        for (int j = 0; j < 4; ++j) eid[j] = pEid[e0 + mq2 + 16 * j];
        float4 fv[4];
        #pragma unroll
        for (int j = 0; j < 4; ++j) fv[j] = ef4[(size_t)eid[j] * 16 + c2];
        #pragma unroll
        for (int j = 0; j < 4; ++j) {
            int mm = mq2 + 16 * j;
            short4v sv;
            sv.x = f2bf_t(fv[j].x); sv.y = f2bf_t(fv[j].y);
            sv.z = f2bf_t(fv[j].z); sv.w = f2bf_t(fv[j].w);
            *(short4v*)&sA[mm * KA_PAD + WIDTH + c2 * 4] = sv;
        }
    }
    __syncthreads();

    // ---- run-head detection (wave 0) ----
    if (tid < 64) {
        bool head = (tid == 0) || (sDst[tid] != sDst[tid - 1]);
        unsigned long long mask = __ballot(head);
        int rank = __popcll(mask & ((1ull << tid) - 1ull));
        if (head) sHeadRow[rank] = tid;
        if (tid == 0) {
            int nh = (int)__popcll(mask);
            sMeta[0] = nh;
            sHeadRow[nh] = MT;
            int prevSame = 0, nextSame = 0;
            if (e0 > 0)           prevSame = (pSD[e0 - 1].y  == (unsigned)sDst[0]);
            if (e0 + MT < NEDGES) nextSame = (pSD[e0 + MT].y == (unsigned)sDst[MT - 1]);
            sMeta[1] = prevSame; sMeta[2] = nextSame;
        }
    }

    // ---- MFMA: 4 waves, wave w -> rows 0..63 x cols [w*32, w*32+32) ----
    const int wave = tid >> 6;
    const int lane = tid & 63;
    const int l15  = lane & 15;
    const int kq   = (lane >> 4) << 3;
    const int quad = lane >> 4;

    floatx4 acc[4][2];
    #pragma unroll
    for (int rt = 0; rt < 4; ++rt)
        #pragma unroll
        for (int ct = 0; ct < 2; ++ct)
            acc[rt][ct] = (floatx4){0.f, 0.f, 0.f, 0.f};

    #pragma unroll
    for (int kc = 0; kc < 6; ++kc) {
        int k0 = kc * 32 + kq;
        short8 a[4];
        #pragma unroll
        for (int rt = 0; rt < 4; ++rt)
            a[rt] = *(const short8*)&sA[(rt * 16 + l15) * KA_PAD + k0];
        short8 b[2];
        #pragma unroll
        for (int ct = 0; ct < 2; ++ct)
            b[ct] = *(const short8*)&We_t[(size_t)(wave * 32 + ct * 16 + l15) * KA + k0];
        #pragma unroll
        for (int rt = 0; rt < 4; ++rt)
            #pragma unroll
            for (int ct = 0; ct < 2; ++ct)
                acc[rt][ct] = __builtin_amdgcn_mfma_f32_16x16x32_bf16(a[rt], b[ct], acc[rt][ct], 0, 0, 0);
    }

    // ---- ef = resid + relu(acc + bias) ----
    #pragma unroll
    for (int rt = 0; rt < 4; ++rt) {
        #pragma unroll
        for (int ct = 0; ct < 2; ++ct) {
            int col = wave * 32 + ct * 16 + l15;
            float bias = sBias[col];
            #pragma unroll
            for (int i = 0; i < 4; ++i) {
                int row = rt * 16 + quad * 4 + i;
                float v = acc[rt][ct][i] + bias;
                v = v > 0.f ? v : 0.f;
                acc[rt][ct][i] = v + bf2f(sA[row * KA_PAD + col]);
            }
        }
    }
    __syncthreads();   // sA reads done; sHeadRow/sMeta published

    // ---- write bf16 result tile COL-MAJOR (stride STC shorts): a lane's 4
    //      accumulator rows are contiguous -> single ds_write_b64
    short* sT = sA;
    #pragma unroll
    for (int rt = 0; rt < 4; ++rt) {
        #pragma unroll
        for (int ct = 0; ct < 2; ++ct) {
            int col = wave * 32 + ct * 16 + l15;
            short4v pk;
            pk.x = f2bf_t(acc[rt][ct][0]);
            pk.y = f2bf_t(acc[rt][ct][1]);
            pk.z = f2bf_t(acc[rt][ct][2]);
            pk.w = f2bf_t(acc[rt][ct][3]);
            *(short4v*)&sT[col * STC + rt * 16 + quad * 4] = pk;
        }
    }
    __syncthreads();

    // ---- segmented max over runs: per (run, col) item, walk the column's
    //      contiguous rows as b32 words (2 rows/read) ----
    const int nh = sMeta[0], prevSame = sMeta[1], nextSame = sMeta[2];
    const unsigned* sT32 = (const unsigned*)sT;
    for (int p = tid; p < (nh << 7); p += 256) {
        int h = p >> 7, c = p & 127;
        int r0 = sHeadRow[h], r1 = sHeadRow[h + 1];
        const unsigned* colp = sT32 + c * (STC / 2);
        int w0 = r0 >> 1, w1 = (r1 - 1) >> 1;
        float m = -3.4e38f;
        for (int w = w0; w <= w1; ++w) {
            unsigned u = colp[w];
            float flo = bf2f((short)(u & 0xffffu));
            float fhi = bf2f((short)(u >> 16));
            if (2 * w >= r0)    m = fmaxf(m, flo);
            if (2 * w + 1 < r1) m = fmaxf(m, fhi);
        }
        int dst = sDst[r0];
        unsigned ev = encu(m);
        unsigned* dp = &mEnc[(size_t)dst * WIDTH + c];
        bool atom = (h == 0 && prevSame) || (h == nh - 1 && nextSame);
        if (atom) atomicMax(dp, ev);
        else      *dp = ev;
    }
}

// ---------------------------------------------------------------------------
// node: out = x + relu([x, maxes] @ W_mlp + b_mlp)
// R15: coalesced float4 epilogue via f32 LDS tile (reuses sA).
// R17: x float4s kept in registers from staging (same (row,col4) thread
// mapping) -> second 51.2MB x-read deleted; node traffic 205->154MB.
// ---------------------------------------------------------------------------
__global__ __launch_bounds__(256) void node_kernel(
    const float* __restrict__ x, const short* __restrict__ Wm_t,
    const float* __restrict__ b_mlp, float* __restrict__ out)
{
    __shared__ __align__(16) short sA[MT * KB_PAD];   // staging; reused as f32 [64][NVPAD] result tile
    __shared__ float sBias[WIDTH];

    const int tid = threadIdx.x;
    if (tid < WIDTH) sBias[tid] = b_mlp[tid];

    const int n0 = blockIdx.x * MT;
    const float4* xf4 = (const float4*)x;
    const uint4* enc4 = (const uint4*)out;

    float4 xvs[8];                      // R17: staged x rows, reused in epilogue
    {
        int mq = tid >> 5, c = tid & 31;
        #pragma unroll
        for (int j = 0; j < 8; ++j) {
            int mm = mq + 8 * j;
            int node = n0 + mm;
            if (node >= NNODES) node = NNODES - 1;
            float4 xv = xf4[(size_t)node * 32 + c];
            xvs[j] = xv;
            short4v sx;
            sx.x = f2bf_rne(xv.x); sx.y = f2bf_rne(xv.y);
            sx.z = f2bf_rne(xv.z); sx.w = f2bf_rne(xv.w);
            *(short4v*)&sA[mm * KB_PAD + c * 4] = sx;
            uint4 ev = enc4[(size_t)node * 32 + c];
            short4v sm;
            sm.x = f2bf_rne(ev.x == 0u ? 0.f : decu(ev.x));
            sm.y = f2bf_rne(ev.y == 0u ? 0.f : decu(ev.y));
            sm.z = f2bf_rne(ev.z == 0u ? 0.f : decu(ev.z));
            sm.w = f2bf_rne(ev.w == 0u ? 0.f : decu(ev.w));
            *(short4v*)&sA[mm * KB_PAD + WIDTH + c * 4] = sm;
        }
    }
    __syncthreads();

    const int wave = tid >> 6;
    const int lane = tid & 63;
    const int l15  = lane & 15;
    const int kq   = (lane >> 4) << 3;
    const int quad = lane >> 4;

    floatx4 acc[4][2];
    #pragma unroll
    for (int rt = 0; rt < 4; ++rt)
        #pragma unroll
        for (int ct = 0; ct < 2; ++ct)
            acc[rt][ct] = (floatx4){0.f, 0.f, 0.f, 0.f};

    #pragma unroll
    for (int kc = 0; kc < 8; ++kc) {
        int k0 = kc * 32 + kq;
        short8 a[4];
        #pragma unroll
        for (int rt = 0; rt < 4; ++rt)
            a[rt] = *(const short8*)&sA[(rt * 16 + l15) * KB_PAD + k0];
        short8 b[2];
        #pragma unroll
        for (int ct = 0; ct < 2; ++ct)
            b[ct] = *(const short8*)&Wm_t[(size_t)(wave * 32 + ct * 16 + l15) * KB + k0];
        #pragma unroll
        for (int rt = 0; rt < 4; ++rt)
            #pragma unroll
            for (int ct = 0; ct < 2; ++ct)
                acc[rt][ct] = __builtin_amdgcn_mfma_f32_16x16x32_bf16(a[rt], b[ct], acc[rt][ct], 0, 0, 0);
    }
    __syncthreads();   // staging reads done; sA reused as f32 tile

    // ---- v = relu(acc + bias) -> LDS f32 tile [MT][NVPAD] ----
    float* sV = (float*)sA;
    #pragma unroll
    for (int rt = 0; rt < 4; ++rt) {
        #pragma unroll
        for (int ct = 0; ct < 2; ++ct) {
            int col = wave * 32 + ct * 16 + l15;
            float bias = sBias[col];
            #pragma unroll
            for (int i = 0; i < 4; ++i) {
                int row = rt * 16 + quad * 4 + i;
                float v = acc[rt][ct][i] + bias;
                sV[row * NVPAD + col] = v > 0.f ? v : 0.f;
            }
        }
    }
    __syncthreads();

    // ---- coalesced epilogue: out = x + v, float4 per lane; x from registers
    {
        int q = tid & 31, r0 = tid >> 5;
        #pragma unroll
        for (int pass = 0; pass < 8; ++pass) {
            int r = r0 + 8 * pass;
            int node = n0 + r;
            if (node < NNODES) {
                float4 xv = xvs[pass];
                const float* vp = &sV[r * NVPAD + q * 4];
                float4 ov;
                ov.x = xv.x + vp[0];
                ov.y = xv.y + vp[1];
                ov.z = xv.z + vp[2];
                ov.w = xv.w + vp[3];
                ((float4*)out)[(size_t)node * 32 + q] = ov;
            }
        }
    }
}

extern "C" void kernel_launch(void* const* d_in, const int* in_sizes, int n_in,
                              void* d_out, int out_size, void* d_ws, size_t ws_size,
                              hipStream_t stream) {
    const float* x      = (const float*)d_in[0];
    const int*   e      = (const int*)d_in[1];
    const float* e_feat = (const float*)d_in[2];
    const float* W_edge = (const float*)d_in[3];
    const float* b_edge = (const float*)d_in[4];
    const float* W_mlp  = (const float*)d_in[5];
    const float* b_mlp  = (const float*)d_in[6];
    float*    out  = (float*)d_out;
    unsigned* mEnc = (unsigned*)d_out;           // segment-max lives in d_out

    short* We_t = (short*)d_ws;                           // [128][192] bf16
    short* Wm_t = We_t + (size_t)KA * WIDTH;              // [128][256] bf16
    int* base     = (int*)((char*)d_ws + 114688);         // 8B-aligned
    uint2* pSD    = (uint2*)base;                         // [E] (src,dst) sorted
    int* pEid     = (int*)(base + 2 * NEDGES);            // [E]
    int* counts   = pEid + NEDGES;                        // [N]
    int* cursor   = counts + NNODES;                      // [N]
    int* blockSum = cursor + NNODES;                      // [NB_SCAN]
    int* blockOff = blockSum + NB_SCAN;                   // [NB_SCAN]

    hipMemsetAsync(d_out, 0, (size_t)NNODES * WIDTH * 4, stream);   // empty = enc 0
    hipMemsetAsync(counts, 0, (size_t)NNODES * 4, stream);
    prep_hist_kernel<<<NB_HIST + NB_PREP, 256, 0, stream>>>(e, counts, W_edge, W_mlp, We_t, Wm_t);
    scanA_kernel<<<NB_SCAN, 256, 0, stream>>>(counts, cursor, blockSum);
    scanB_kernel<<<1, 512, 0, stream>>>(blockSum, blockOff);
    scatter_kernel<<<(NEDGES + 255) / 256, 256, 0, stream>>>(e, cursor, blockOff, pSD, pEid);
    edge_kernel<<<NEDGES / MT, 256, 0, stream>>>(x, e_feat, We_t, b_edge, pSD, pEid, mEnc);
    node_kernel<<<(NNODES + MT - 1) / MT, 256, 0, stream>>>(x, Wm_t, b_mlp, out);
}